// Round 21
// baseline (265.885 us; speedup 1.0000x reference)
//
#include <hip/hip_runtime.h>

// Problem constants: Bq=128, Bk=128, Nk=256, C=1024, H=16, hd=64, scale=0.125, eps=1e-5.

typedef unsigned short ushort_t;
typedef __bf16 bf16x8 __attribute__((ext_vector_type(8)));
typedef float f32x4 __attribute__((ext_vector_type(4)));

#define AS1 __attribute__((address_space(1)))
#define AS3 __attribute__((address_space(3)))

__device__ __forceinline__ void gload_lds16(const void* g, void* l) {
  __builtin_amdgcn_global_load_lds((const AS1 unsigned int*)g, (AS3 unsigned int*)l, 16, 0, 0);
}

__device__ __forceinline__ ushort_t f2bf(float f) {
  unsigned u = __float_as_uint(f);
  unsigned r = u + 0x7FFFu + ((u >> 16) & 1u);
  return (ushort_t)(r >> 16);
}

// ---------------------------------------------------------------------------
// K0: fp32 -> bf16 convert, BOTH weights in one dispatch.
// ---------------------------------------------------------------------------
__global__ __launch_bounds__(256) void cvt_bf16_kernel(const float* __restrict__ Wq,
                                                       const float* __restrict__ Wk,
                                                       ushort_t* __restrict__ Wqb,
                                                       ushort_t* __restrict__ Wkb) {
  const float* src; ushort_t* dst; int i;
  if (blockIdx.x < 1024) {
    src = Wq; dst = Wqb; i = blockIdx.x * 256 + threadIdx.x;
  } else {
    src = Wk; dst = Wkb; i = (blockIdx.x - 1024) * 256 + threadIdx.x;
  }
  float4 v = ((const float4*)src)[i];
  ushort4 o;
  o.x = f2bf(v.x); o.y = f2bf(v.y); o.z = f2bf(v.z); o.w = f2bf(v.w);
  ((ushort4*)dst)[i] = o;
}

// ---------------------------------------------------------------------------
// K1: LayerNorm, ONE WAVE PER ROW, no barriers, no LDS (r15-verified body).
// ---------------------------------------------------------------------------
__global__ __launch_bounds__(256) void ln_kernel(const float* __restrict__ kx,
                                                 const float* __restrict__ qx,
                                                 const float* __restrict__ gk,
                                                 const float* __restrict__ bk,
                                                 const float* __restrict__ gq,
                                                 const float* __restrict__ bq,
                                                 ushort_t* __restrict__ kln,
                                                 ushort_t* __restrict__ qln) {
  const int tid = threadIdx.x, lane = tid & 63, wid = tid >> 6;

  const float* src; ushort_t* dst; const float* gp; const float* bp;
  if (blockIdx.x < 8192) {
    const int row = blockIdx.x * 4 + wid;
    src = kx + (size_t)row * 1024; dst = kln + (size_t)row * 1024; gp = gk; bp = bk;
  } else {
    const int row = (blockIdx.x - 8192) * 4 + wid;
    src = qx + (size_t)row * 1024; dst = qln + (size_t)row * 1024; gp = gq; bp = bq;
  }
  const int c0 = lane * 4;

  float4 v0 = *(const float4*)(src + c0);
  float4 v1 = *(const float4*)(src + c0 + 256);
  float4 v2 = *(const float4*)(src + c0 + 512);
  float4 v3 = *(const float4*)(src + c0 + 768);

  float s  = (v0.x + v0.y + v0.z + v0.w) + (v1.x + v1.y + v1.z + v1.w)
           + (v2.x + v2.y + v2.z + v2.w) + (v3.x + v3.y + v3.z + v3.w);
  float s2 = (v0.x*v0.x + v0.y*v0.y + v0.z*v0.z + v0.w*v0.w)
           + (v1.x*v1.x + v1.y*v1.y + v1.z*v1.z + v1.w*v1.w)
           + (v2.x*v2.x + v2.y*v2.y + v2.z*v2.z + v2.w*v2.w)
           + (v3.x*v3.x + v3.y*v3.y + v3.z*v3.z + v3.w*v3.w);
  #pragma unroll
  for (int off = 1; off < 64; off <<= 1) {
    s  += __shfl_xor(s, off);
    s2 += __shfl_xor(s2, off);
  }
  const float mean = s * (1.0f / 1024.0f);
  const float var  = s2 * (1.0f / 1024.0f) - mean * mean;
  const float rstd = rsqrtf(var + 1e-5f);

  float4 g0 = *(const float4*)(gp + c0);
  float4 g1 = *(const float4*)(gp + c0 + 256);
  float4 g2 = *(const float4*)(gp + c0 + 512);
  float4 g3 = *(const float4*)(gp + c0 + 768);
  float4 b0 = *(const float4*)(bp + c0);
  float4 b1 = *(const float4*)(bp + c0 + 256);
  float4 b2 = *(const float4*)(bp + c0 + 512);
  float4 b3 = *(const float4*)(bp + c0 + 768);

  ushort4 o0, o1, o2, o3;
  o0.x = f2bf((v0.x - mean) * rstd * g0.x + b0.x);
  o0.y = f2bf((v0.y - mean) * rstd * g0.y + b0.y);
  o0.z = f2bf((v0.z - mean) * rstd * g0.z + b0.z);
  o0.w = f2bf((v0.w - mean) * rstd * g0.w + b0.w);
  o1.x = f2bf((v1.x - mean) * rstd * g1.x + b1.x);
  o1.y = f2bf((v1.y - mean) * rstd * g1.y + b1.y);
  o1.z = f2bf((v1.z - mean) * rstd * g1.z + b1.z);
  o1.w = f2bf((v1.w - mean) * rstd * g1.w + b1.w);
  o2.x = f2bf((v2.x - mean) * rstd * g2.x + b2.x);
  o2.y = f2bf((v2.y - mean) * rstd * g2.y + b2.y);
  o2.z = f2bf((v2.z - mean) * rstd * g2.z + b2.z);
  o2.w = f2bf((v2.w - mean) * rstd * g2.w + b2.w);
  o3.x = f2bf((v3.x - mean) * rstd * g3.x + b3.x);
  o3.y = f2bf((v3.y - mean) * rstd * g3.y + b3.y);
  o3.z = f2bf((v3.z - mean) * rstd * g3.z + b3.z);
  o3.w = f2bf((v3.w - mean) * rstd * g3.w + b3.w);

  *(ushort4*)(dst + c0)       = o0;
  *(ushort4*)(dst + c0 + 256) = o1;
  *(ushort4*)(dst + c0 + 512) = o2;
  *(ushort4*)(dst + c0 + 768) = o3;
}

// ---------------------------------------------------------------------------
// K3: K-projection GEMM — r17 counted-vmcnt structure at BK=32, LDS 80KB
// (A 3-buf dist-2 + B 2-buf dist-1, 16KB each) -> 2 BLOCKS/CU, 16 waves/CU.
// Per K-step (32 total): 12 ds_read + stB(j+1)[2] + stA(j+2)[2] + 32 MFMA +
// vmcnt(2) + ONE barrier.  FIFO: vmcnt(2) retires A(j+1),B(j+1), leaves
// A(j+2) in flight.  Swizzle gs=(ix&3)^(r&3) -> 2-way read banks (free).
// + r12's spread Q-projection coda (64 blocks, one 16x16 tile per wave).
// Launch bound (512,2): cap 256 VGPR — (512,4) spilled 30x (r9).
// ---------------------------------------------------------------------------
__global__ __launch_bounds__(512, 2) void gemm256_kernel(const ushort_t* __restrict__ A,
                                                         const ushort_t* __restrict__ Bt,
                                                         ushort_t* __restrict__ Cpk,
                                                         const ushort_t* __restrict__ qA,
                                                         const ushort_t* __restrict__ qB,
                                                         ushort_t* __restrict__ qC,
                                                         int M, int N) {
  __shared__ ushort_t Abuf[3][8192];   // 3 x 256x32 bf16 = 48KB
  __shared__ ushort_t Bbuf[2][8192];   // 2 x 256x32 bf16 = 32KB

  const int tid = threadIdx.x, lane = tid & 63, wid = tid >> 6;
  const int g = lane >> 4, rr = lane & 15;
  const int wr = wid >> 2, wc = wid & 3;

  const int Mt = M >> 8, Nt = N >> 8;
  const int nwg = Mt * Nt;
  const int qq = nwg >> 3, r8 = nwg & 7;
  const int xcd = blockIdx.x & 7, idx = blockIdx.x >> 3;
  const int wg = (xcd < r8 ? xcd * (qq + 1) : r8 * (qq + 1) + (xcd - r8) * qq) + idx;
  const int mt = wg / Nt, nt = wg - mt * Nt;
  const size_t m0 = (size_t)mt << 8, n0 = (size_t)nt << 8;

  const ushort_t* Abase = A  + m0 * 1024;
  const ushort_t* Bbase = Bt + n0 * 1024;

  f32x4 acc[8][4];
  #pragma unroll
  for (int i = 0; i < 8; ++i)
    #pragma unroll
    for (int j = 0; j < 4; ++j) acc[i][j] = (f32x4){0.f, 0.f, 0.f, 0.f};

  // stage one 256x32 K-step tile: 2 gload_lds/thread, lane-linear LDS dst.
  auto stA = [&](int kt) {
    ushort_t* dst = &Abuf[kt % 3][0];
    #pragma unroll
    for (int l = 0; l < 2; ++l) {
      int ix = l * 512 + tid;          // 0..1023
      int r  = ix >> 2;                // row 0..255
      int gs = (ix & 3) ^ (r & 3);     // pre-swizzled global granule
      gload_lds16(Abase + (size_t)r * 1024 + (kt << 5) + (gs << 3), dst + ix * 8);
    }
  };
  auto stB = [&](int kt) {
    ushort_t* dst = &Bbuf[kt & 1][0];
    #pragma unroll
    for (int l = 0; l < 2; ++l) {
      int ix = l * 512 + tid;
      int r  = ix >> 2;
      int gs = (ix & 3) ^ (r & 3);
      gload_lds16(Bbase + (size_t)r * 1024 + (kt << 5) + (gs << 3), dst + ix * 8);
    }
  };

  // prologue: A0, B0, A1 in flight (6 loads); retire A0,B0; keep A1.
  stA(0); stB(0); stA(1);
  asm volatile("s_waitcnt vmcnt(2)" ::: "memory");
  __builtin_amdgcn_s_barrier();

  #pragma unroll 1
  for (int j = 0; j < 32; ++j) {
    const ushort_t* as = &Abuf[j % 3][0];
    const ushort_t* bs = &Bbuf[j & 1][0];

    bf16x8 af[8], bf[4];
    #pragma unroll
    for (int i = 0; i < 8; ++i) {
      int r = (wr << 7) + (i << 4) + rr;
      af[i] = *(const bf16x8*)&as[(r << 5) + ((g ^ (r & 3)) << 3)];
    }
    #pragma unroll
    for (int jj = 0; jj < 4; ++jj) {
      int r = (wc << 6) + (jj << 4) + rr;
      bf[jj] = *(const bf16x8*)&bs[(r << 5) + ((g ^ (r & 3)) << 3)];
    }
    if (j < 31) stB(j + 1);
    if (j < 30) stA(j + 2);
    __builtin_amdgcn_s_setprio(1);
    #pragma unroll
    for (int i = 0; i < 8; ++i)
      #pragma unroll
      for (int jj = 0; jj < 4; ++jj)
        acc[i][jj] = __builtin_amdgcn_mfma_f32_16x16x32_bf16(af[i], bf[jj], acc[i][jj], 0, 0, 0);
    __builtin_amdgcn_s_setprio(0);
    if (j < 30) {
      asm volatile("s_waitcnt vmcnt(2)" ::: "memory");
      __builtin_amdgcn_s_barrier();
    } else if (j == 30) {
      asm volatile("s_waitcnt vmcnt(0)" ::: "memory");
      __builtin_amdgcn_s_barrier();
    }
  }

  // packed epilogue: idx = ((kb*16+h)*16+t)*1024 + half*512 + g*128 + r16*8 + e
  #pragma unroll
  for (int i = 0; i < 8; ++i)
    #pragma unroll
    for (int j = 0; j < 4; ++j)
      #pragma unroll
      for (int rg = 0; rg < 4; ++rg) {
        size_t row = m0 + (wr << 7) + (i << 4) + (g << 2) + rg;
        size_t col = n0 + (wc << 6) + (j << 4) + rr;
        int kb = (int)(row >> 8), t = (int)((row >> 4) & 15), r16 = (int)(row & 15);
        int h = (int)(col >> 6), ch = (int)(col & 63);
        size_t odx = ((((size_t)kb * 16 + h) * 16 + t) << 10)
                   + ((ch >> 5) << 9) + (((ch >> 3) & 3) << 7) + (r16 << 3) + (ch & 7);
        Cpk[odx] = f2bf(acc[i][j][rg]);
      }

  // ---------------- Q-projection coda: 64 blocks, one tile PER WAVE (r12) ----------------
  if ((wg & 63) < 8) {
    const int ti = ((wg >> 6) << 6) + ((wg & 7) << 3) + wid;   // 0..511, bijective
    const int mq = ti >> 6, nq = ti & 63;
    const ushort_t* qa = qA + (size_t)(mq * 16 + rr) * 1024 + g * 8;
    const ushort_t* qb = qB + (size_t)(nq * 16 + rr) * 1024 + g * 8;
    f32x4 qacc0 = (f32x4){0.f, 0.f, 0.f, 0.f};
    f32x4 qacc1 = (f32x4){0.f, 0.f, 0.f, 0.f};
    #pragma unroll
    for (int kk = 0; kk < 32; kk += 2) {
      bf16x8 a0 = *(const bf16x8*)(qa + kk * 32);
      bf16x8 b0 = *(const bf16x8*)(qb + kk * 32);
      bf16x8 a1 = *(const bf16x8*)(qa + kk * 32 + 32);
      bf16x8 b1 = *(const bf16x8*)(qb + kk * 32 + 32);
      qacc0 = __builtin_amdgcn_mfma_f32_16x16x32_bf16(a0, b0, qacc0, 0, 0, 0);
      qacc1 = __builtin_amdgcn_mfma_f32_16x16x32_bf16(a1, b1, qacc1, 0, 0, 0);
    }
    #pragma unroll
    for (int rg = 0; rg < 4; ++rg)
      qC[(size_t)(mq * 16 + (g << 2) + rg) * 1024 + nq * 16 + rr] = f2bf(qacc0[rg] + qacc1[rg]);
  }
}

// ---------------------------------------------------------------------------
// K4a: scores kernel (unchanged: packed K loads, static indexing).
// ---------------------------------------------------------------------------
__global__ __launch_bounds__(256, 3) void scores_kernel(const ushort_t* __restrict__ qp,   // [128][1024]
                                                        const ushort_t* __restrict__ kpk,  // packed
                                                        ushort_t* __restrict__ wbuf) {     // [128][128][256]
  __shared__ float pbuf[2][16][258];

  const int tid = threadIdx.x, lane = tid & 63, wid = tid >> 6;
  const int g = lane >> 4, rr = lane & 15;

  const int b = blockIdx.x;
  const int wg = (b & 7) * 128 + (b >> 3);
  const int kb = wg >> 3;
  const int q0 = (wg & 7) << 4;

  const int hs = wid;

  float w_acc[16][4];
  #pragma unroll
  for (int t = 0; t < 16; ++t)
    #pragma unroll
    for (int r = 0; r < 4; ++r) w_acc[t][r] = 0.f;

  const ushort_t* qrow = qp + (size_t)(q0 + rr) * 1024;
  const ushort_t* kbb  = kpk + ((size_t)kb * 16) * 16384 + g * 128 + rr * 8;

  for (int hp = 0; hp < 4; ++hp) {
    const int h = hp * 4 + hs;
    const int co = h * 64 + g * 8;
    bf16x8 aq0 = *(const bf16x8*)(qrow + co);
    bf16x8 aq1 = *(const bf16x8*)(qrow + co + 32);
    const ushort_t* hb = kbb + (size_t)h * 16384;
    f32x4 s[16];
    #pragma unroll
    for (int t = 0; t < 16; ++t) {
      bf16x8 b0 = *(const bf16x8*)(hb + t * 1024);
      bf16x8 b1 = *(const bf16x8*)(hb + t * 1024 + 512);
      f32x4 a = (f32x4){0.f, 0.f, 0.f, 0.f};
      a = __builtin_amdgcn_mfma_f32_16x16x32_bf16(aq0, b0, a, 0, 0, 0);
      a = __builtin_amdgcn_mfma_f32_16x16x32_bf16(aq1, b1, a, 0, 0, 0);
      s[t] = a;
    }
    #pragma unroll
    for (int r = 0; r < 4; ++r) {
      float mx = s[0][r];
      #pragma unroll
      for (int t = 1; t < 16; ++t) mx = fmaxf(mx, s[t][r]);
      mx = fmaxf(mx, __shfl_xor(mx, 1));
      mx = fmaxf(mx, __shfl_xor(mx, 2));
      mx = fmaxf(mx, __shfl_xor(mx, 4));
      mx = fmaxf(mx, __shfl_xor(mx, 8));
      float sum = 0.f;
      float e[16];
      #pragma unroll
      for (int t = 0; t < 16; ++t) {
        e[t] = __expf((s[t][r] - mx) * 0.125f);
        sum += e[t];
      }
      sum += __shfl_xor(sum, 1);
      sum += __shfl_xor(sum, 2);
      sum += __shfl_xor(sum, 4);
      sum += __shfl_xor(sum, 8);
      float inv = 1.0f / sum;
      #pragma unroll
      for (int t = 0; t < 16; ++t) w_acc[t][r] += e[t] * inv;
    }
  }

  __syncthreads();
  if (hs >= 2) {
    #pragma unroll
    for (int t = 0; t < 16; ++t)
      #pragma unroll
      for (int r = 0; r < 4; ++r)
        pbuf[hs - 2][(g << 2) + r][t * 16 + rr] = w_acc[t][r];
  }
  __syncthreads();
  if (hs < 2) {
    #pragma unroll
    for (int t = 0; t < 16; ++t)
      #pragma unroll
      for (int r = 0; r < 4; ++r)
        w_acc[t][r] += pbuf[hs][(g << 2) + r][t * 16 + rr];
    if (hs == 1) {
      #pragma unroll
      for (int t = 0; t < 16; ++t)
        #pragma unroll
        for (int r = 0; r < 4; ++r)
          pbuf[1][(g << 2) + r][t * 16 + rr] = w_acc[t][r];
    }
  }
  __syncthreads();
  if (hs == 0) {
    ushort_t* wb = wbuf + (size_t)kb * 32768;
    #pragma unroll
    for (int t = 0; t < 16; ++t)
      #pragma unroll
      for (int r = 0; r < 4; ++r) {
        float v = w_acc[t][r] + pbuf[1][(g << 2) + r][t * 16 + rr];
        wb[(size_t)(q0 + (g << 2) + r) * 256 + t * 16 + rr] = f2bf(v);
      }
  }
}

// ---------------------------------------------------------------------------
// K4b: PV kernel (r12 version — measured-good).
// ---------------------------------------------------------------------------
__global__ __launch_bounds__(256, 4) void pv_kernel(const ushort_t* __restrict__ wbuf, // [128][128][256]
                                                    const float* __restrict__ kx,      // [32768][1024]
                                                    float* __restrict__ xout) {        // [128][128][1024]
  const int tid = threadIdx.x, lane = tid & 63, wid = tid >> 6;
  const int g = lane >> 4, rr = lane & 15;

  const int b = blockIdx.x;
  const int wg = (b & 7) * 128 + (b >> 3);
  const int kb = wg >> 3;
  const int c0 = (wg & 7) * 128;

  const int wr = wid >> 1, wc = wid & 1;

  f32x4 acc[4][4];
  #pragma unroll
  for (int i = 0; i < 4; ++i)
    #pragma unroll
    for (int j = 0; j < 4; ++j) acc[i][j] = (f32x4){0.f, 0.f, 0.f, 0.f};

  const ushort_t* wb = wbuf + (size_t)kb * 32768;
  const float* kxb = kx + (size_t)kb * 256 * 1024;

  for (int nc = 0; nc < 8; ++nc) {
    const int n0 = nc * 32 + g * 8;
    bf16x8 af[4];
    #pragma unroll
    for (int i = 0; i < 4; ++i) {
      int q = (wr << 6) + (i << 4) + rr;
      af[i] = *(const bf16x8*)(wb + (size_t)q * 256 + n0);
    }
    #pragma unroll
    for (int j = 0; j < 4; ++j) {
      int c = c0 + (wc << 6) + (j << 4) + rr;
      const float* src = kxb + (size_t)n0 * 1024 + c;
      float f[8];
      #pragma unroll
      for (int jj = 0; jj < 8; ++jj) f[jj] = src[(size_t)jj * 1024];
      bf16x8 bb;
      #pragma unroll
      for (int jj = 0; jj < 8; ++jj) bb[jj] = (__bf16)f[jj];
      #pragma unroll
      for (int i = 0; i < 4; ++i)
        acc[i][j] = __builtin_amdgcn_mfma_f32_16x16x32_bf16(af[i], bb, acc[i][j], 0, 0, 0);
    }
  }

  #pragma unroll
  for (int i = 0; i < 4; ++i)
    #pragma unroll
    for (int j = 0; j < 4; ++j)
      #pragma unroll
      for (int rg = 0; rg < 4; ++rg) {
        int q = (wr << 6) + (i << 4) + (g << 2) + rg;
        int c = c0 + (wc << 6) + (j << 4) + rr;
        xout[((size_t)q * 128 + kb) * 1024 + c] = acc[i][j][rg];
      }
}

// ---------------------------------------------------------------------------
// launcher
// ---------------------------------------------------------------------------
extern "C" void kernel_launch(void* const* d_in, const int* in_sizes, int n_in,
                              void* d_out, int out_size, void* d_ws, size_t ws_size,
                              hipStream_t stream) {
  const float* qx = (const float*)d_in[0];
  const float* kx = (const float*)d_in[1];
  const float* gq = (const float*)d_in[2];
  const float* bq = (const float*)d_in[3];
  const float* gk = (const float*)d_in[4];
  const float* bk = (const float*)d_in[5];
  const float* Wq = (const float*)d_in[6];
  const float* Wk = (const float*)d_in[7];

  char* ws = (char*)d_ws;
  // ws layout (total 72.25 MiB, r12 scheme):
  //   [0, 64M)            kkp   : PACKED K-projection bf16 (live: gemm256 -> scores)
  //   [64M, 64M+256K)     qproj : Q-projection bf16 [128][1024] (live: gemm256 -> scores)
  //   [64M+256K, +8M)     wbuf  : head-summed weights bf16 [128][128][256] (live: scores -> pv)
  //     aliased inside wbuf (dead before scores runs):
  //       qln @wbuf+0      [128][1024] bf16  (live: ln -> gemm256 coda)
  //       Wqb @wbuf+256K   [1024][1024] bf16 (live: cvt -> gemm256 coda)
  //       Wkb @wbuf+2.25M  [1024][1024] bf16 (live: cvt -> gemm256)
  ushort_t* kkp   = (ushort_t*)(ws);
  ushort_t* qproj = (ushort_t*)(ws + 67108864);
  ushort_t* wbuf  = (ushort_t*)(ws + 67371008);
  ushort_t* qln   = (ushort_t*)(ws + 67371008);
  ushort_t* Wqb   = (ushort_t*)(ws + 67371008 + 262144);
  ushort_t* Wkb   = (ushort_t*)(ws + 67371008 + 2359296);
  // kln (bf16, 64 MiB) lives in d_out; dead after gemm256, overwritten by pv.
  ushort_t* kln  = (ushort_t*)d_out;
  float*    xout = (float*)d_out;

  cvt_bf16_kernel<<<2048, 256, 0, stream>>>(Wq, Wk, Wqb, Wkb);
  ln_kernel<<<8192 + 32, 256, 0, stream>>>(kx, qx, gk, bk, gq, bq, kln, qln);
  gemm256_kernel<<<512, 512, 0, stream>>>(kln, Wkb, kkp, qln, Wqb, qproj, 32768, 1024);
  scores_kernel<<<1024, 256, 0, stream>>>(qproj, kkp, wbuf);
  pv_kernel<<<1024, 256, 0, stream>>>(wbuf, kx, xout);
}

// Round 22
// 260.597 us; speedup vs baseline: 1.0203x; 1.0203x over previous
//
#include <hip/hip_runtime.h>

// Problem constants: Bq=128, Bk=128, Nk=256, C=1024, H=16, hd=64, scale=0.125, eps=1e-5.

typedef unsigned short ushort_t;
typedef __bf16 bf16x8 __attribute__((ext_vector_type(8)));
typedef float f32x4 __attribute__((ext_vector_type(4)));

#define AS1 __attribute__((address_space(1)))
#define AS3 __attribute__((address_space(3)))

__device__ __forceinline__ void gload_lds16(const void* g, void* l) {
  __builtin_amdgcn_global_load_lds((const AS1 unsigned int*)g, (AS3 unsigned int*)l, 16, 0, 0);
}

__device__ __forceinline__ ushort_t f2bf(float f) {
  unsigned u = __float_as_uint(f);
  unsigned r = u + 0x7FFFu + ((u >> 16) & 1u);
  return (ushort_t)(r >> 16);
}

// ---------------------------------------------------------------------------
// K0: fp32 -> bf16 convert, BOTH weights in one dispatch.
// ---------------------------------------------------------------------------
__global__ __launch_bounds__(256) void cvt_bf16_kernel(const float* __restrict__ Wq,
                                                       const float* __restrict__ Wk,
                                                       ushort_t* __restrict__ Wqb,
                                                       ushort_t* __restrict__ Wkb) {
  const float* src; ushort_t* dst; int i;
  if (blockIdx.x < 1024) {
    src = Wq; dst = Wqb; i = blockIdx.x * 256 + threadIdx.x;
  } else {
    src = Wk; dst = Wkb; i = (blockIdx.x - 1024) * 256 + threadIdx.x;
  }
  float4 v = ((const float4*)src)[i];
  ushort4 o;
  o.x = f2bf(v.x); o.y = f2bf(v.y); o.z = f2bf(v.z); o.w = f2bf(v.w);
  ((ushort4*)dst)[i] = o;
}

// ---------------------------------------------------------------------------
// K1: LayerNorm, ONE WAVE PER ROW, no barriers, no LDS (r15-verified body).
//  blocks 0..8191  : kx rows  -> kln  (gk, bk)
//  blocks 8192..   : qx rows  -> qln  (gq, bq)   (32 blocks, 128 rows)
// ---------------------------------------------------------------------------
__global__ __launch_bounds__(256) void ln_kernel(const float* __restrict__ kx,
                                                 const float* __restrict__ qx,
                                                 const float* __restrict__ gk,
                                                 const float* __restrict__ bk,
                                                 const float* __restrict__ gq,
                                                 const float* __restrict__ bq,
                                                 ushort_t* __restrict__ kln,
                                                 ushort_t* __restrict__ qln) {
  const int tid = threadIdx.x, lane = tid & 63, wid = tid >> 6;

  const float* src; ushort_t* dst; const float* gp; const float* bp;
  if (blockIdx.x < 8192) {
    const int row = blockIdx.x * 4 + wid;
    src = kx + (size_t)row * 1024; dst = kln + (size_t)row * 1024; gp = gk; bp = bk;
  } else {
    const int row = (blockIdx.x - 8192) * 4 + wid;
    src = qx + (size_t)row * 1024; dst = qln + (size_t)row * 1024; gp = gq; bp = bq;
  }
  const int c0 = lane * 4;

  float4 v0 = *(const float4*)(src + c0);
  float4 v1 = *(const float4*)(src + c0 + 256);
  float4 v2 = *(const float4*)(src + c0 + 512);
  float4 v3 = *(const float4*)(src + c0 + 768);

  float s  = (v0.x + v0.y + v0.z + v0.w) + (v1.x + v1.y + v1.z + v1.w)
           + (v2.x + v2.y + v2.z + v2.w) + (v3.x + v3.y + v3.z + v3.w);
  float s2 = (v0.x*v0.x + v0.y*v0.y + v0.z*v0.z + v0.w*v0.w)
           + (v1.x*v1.x + v1.y*v1.y + v1.z*v1.z + v1.w*v1.w)
           + (v2.x*v2.x + v2.y*v2.y + v2.z*v2.z + v2.w*v2.w)
           + (v3.x*v3.x + v3.y*v3.y + v3.z*v3.z + v3.w*v3.w);
  #pragma unroll
  for (int off = 1; off < 64; off <<= 1) {
    s  += __shfl_xor(s, off);
    s2 += __shfl_xor(s2, off);
  }
  const float mean = s * (1.0f / 1024.0f);
  const float var  = s2 * (1.0f / 1024.0f) - mean * mean;
  const float rstd = rsqrtf(var + 1e-5f);

  float4 g0 = *(const float4*)(gp + c0);
  float4 g1 = *(const float4*)(gp + c0 + 256);
  float4 g2 = *(const float4*)(gp + c0 + 512);
  float4 g3 = *(const float4*)(gp + c0 + 768);
  float4 b0 = *(const float4*)(bp + c0);
  float4 b1 = *(const float4*)(bp + c0 + 256);
  float4 b2 = *(const float4*)(bp + c0 + 512);
  float4 b3 = *(const float4*)(bp + c0 + 768);

  ushort4 o0, o1, o2, o3;
  o0.x = f2bf((v0.x - mean) * rstd * g0.x + b0.x);
  o0.y = f2bf((v0.y - mean) * rstd * g0.y + b0.y);
  o0.z = f2bf((v0.z - mean) * rstd * g0.z + b0.z);
  o0.w = f2bf((v0.w - mean) * rstd * g0.w + b0.w);
  o1.x = f2bf((v1.x - mean) * rstd * g1.x + b1.x);
  o1.y = f2bf((v1.y - mean) * rstd * g1.y + b1.y);
  o1.z = f2bf((v1.z - mean) * rstd * g1.z + b1.z);
  o1.w = f2bf((v1.w - mean) * rstd * g1.w + b1.w);
  o2.x = f2bf((v2.x - mean) * rstd * g2.x + b2.x);
  o2.y = f2bf((v2.y - mean) * rstd * g2.y + b2.y);
  o2.z = f2bf((v2.z - mean) * rstd * g2.z + b2.z);
  o2.w = f2bf((v2.w - mean) * rstd * g2.w + b2.w);
  o3.x = f2bf((v3.x - mean) * rstd * g3.x + b3.x);
  o3.y = f2bf((v3.y - mean) * rstd * g3.y + b3.y);
  o3.z = f2bf((v3.z - mean) * rstd * g3.z + b3.z);
  o3.w = f2bf((v3.w - mean) * rstd * g3.w + b3.w);

  *(ushort4*)(dst + c0)       = o0;
  *(ushort4*)(dst + c0 + 256) = o1;
  *(ushort4*)(dst + c0 + 512) = o2;
  *(ushort4*)(dst + c0 + 768) = o3;
}

// ---------------------------------------------------------------------------
// K3: K-projection GEMM (r17/r20 coarse counted-vmcnt schedule, BK=64 —
// measured best 83-89us across 6 schedule variants) + r12's spread Q-coda.
// REFUTED alternatives (measured): 4-phase barriers (r19, 95), BK=32 2-blk/CU
// (r21, 95.5), 2-buf vmcnt (r10, 119), B-from-regs (r13, 98).
// Launch bound (512,2): cap 256 VGPR — (512,4) spilled 30x (r9).
// ---------------------------------------------------------------------------
__global__ __launch_bounds__(512, 2) void gemm256_kernel(const ushort_t* __restrict__ A,
                                                         const ushort_t* __restrict__ Bt,
                                                         ushort_t* __restrict__ Cpk,
                                                         const ushort_t* __restrict__ qA,
                                                         const ushort_t* __restrict__ qB,
                                                         ushort_t* __restrict__ qC,
                                                         int M, int N) {
  __shared__ ushort_t Abuf[3][16384];   // 3 x 256x64 bf16 = 96KB
  __shared__ ushort_t Bbuf[2][16384];   // 2 x 256x64 bf16 = 64KB

  const int tid = threadIdx.x, lane = tid & 63, wid = tid >> 6;
  const int g = lane >> 4, rr = lane & 15;
  const int wr = wid >> 2, wc = wid & 3;

  const int Mt = M >> 8, Nt = N >> 8;
  const int nwg = Mt * Nt;
  const int qq = nwg >> 3, r8 = nwg & 7;
  const int xcd = blockIdx.x & 7, idx = blockIdx.x >> 3;
  const int wg = (xcd < r8 ? xcd * (qq + 1) : r8 * (qq + 1) + (xcd - r8) * qq) + idx;
  const int mt = wg / Nt, nt = wg - mt * Nt;
  const size_t m0 = (size_t)mt << 8, n0 = (size_t)nt << 8;

  const ushort_t* Abase = A  + m0 * 1024;
  const ushort_t* Bbase = Bt + n0 * 1024;

  f32x4 acc[8][4];
  #pragma unroll
  for (int i = 0; i < 8; ++i)
    #pragma unroll
    for (int j = 0; j < 4; ++j) acc[i][j] = (f32x4){0.f, 0.f, 0.f, 0.f};

  auto stA = [&](int kt) {
    ushort_t* dst = &Abuf[kt % 3][0];
    #pragma unroll
    for (int l = 0; l < 4; ++l) {
      int ix = l * 512 + tid;
      int r  = ix >> 3;
      int gs = (ix & 7) ^ (((r >> 2) & 1) << 1);
      gload_lds16(Abase + (size_t)r * 1024 + (kt << 6) + (gs << 3), dst + ix * 8);
    }
  };
  auto stB = [&](int kt) {
    ushort_t* dst = &Bbuf[kt & 1][0];
    #pragma unroll
    for (int l = 0; l < 4; ++l) {
      int ix = l * 512 + tid;
      int r  = ix >> 3;
      int gs = (ix & 7) ^ (((r >> 2) & 1) << 1);
      gload_lds16(Bbase + (size_t)r * 1024 + (kt << 6) + (gs << 3), dst + ix * 8);
    }
  };

  stA(0); stB(0); stA(1);
  asm volatile("s_waitcnt vmcnt(4)" ::: "memory");
  __builtin_amdgcn_s_barrier();

  const int sw = ((rr >> 2) & 1) << 1;

  #pragma unroll 1
  for (int j = 0; j < 16; ++j) {
    const ushort_t* as = &Abuf[j % 3][0];
    const ushort_t* bs = &Bbuf[j & 1][0];

    {
      bf16x8 af[8], bf[4];
      #pragma unroll
      for (int i = 0; i < 8; ++i) {
        int r = (wr << 7) + (i << 4) + rr;
        af[i] = *(const bf16x8*)&as[(r << 6) + ((g ^ sw) << 3)];
      }
      #pragma unroll
      for (int jj = 0; jj < 4; ++jj) {
        int r = (wc << 6) + (jj << 4) + rr;
        bf[jj] = *(const bf16x8*)&bs[(r << 6) + ((g ^ sw) << 3)];
      }
      if (j < 15) stB(j + 1);
      if (j < 14) stA(j + 2);
      __builtin_amdgcn_s_setprio(1);
      #pragma unroll
      for (int i = 0; i < 8; ++i)
        #pragma unroll
        for (int jj = 0; jj < 4; ++jj)
          acc[i][jj] = __builtin_amdgcn_mfma_f32_16x16x32_bf16(af[i], bf[jj], acc[i][jj], 0, 0, 0);
      __builtin_amdgcn_s_setprio(0);
    }
    {
      bf16x8 af[8], bf[4];
      #pragma unroll
      for (int i = 0; i < 8; ++i) {
        int r = (wr << 7) + (i << 4) + rr;
        af[i] = *(const bf16x8*)&as[(r << 6) + (((4 + g) ^ sw) << 3)];
      }
      #pragma unroll
      for (int jj = 0; jj < 4; ++jj) {
        int r = (wc << 6) + (jj << 4) + rr;
        bf[jj] = *(const bf16x8*)&bs[(r << 6) + (((4 + g) ^ sw) << 3)];
      }
      __builtin_amdgcn_s_setprio(1);
      #pragma unroll
      for (int i = 0; i < 8; ++i)
        #pragma unroll
        for (int jj = 0; jj < 4; ++jj)
          acc[i][jj] = __builtin_amdgcn_mfma_f32_16x16x32_bf16(af[i], bf[jj], acc[i][jj], 0, 0, 0);
      __builtin_amdgcn_s_setprio(0);
      if (j < 14) {
        asm volatile("s_waitcnt vmcnt(4)" ::: "memory");
        __builtin_amdgcn_s_barrier();
      } else if (j == 14) {
        asm volatile("s_waitcnt vmcnt(0)" ::: "memory");
        __builtin_amdgcn_s_barrier();
      }
    }
  }

  // packed epilogue: idx = ((kb*16+h)*16+t)*1024 + half*512 + g*128 + r16*8 + e
  #pragma unroll
  for (int i = 0; i < 8; ++i)
    #pragma unroll
    for (int j = 0; j < 4; ++j)
      #pragma unroll
      for (int rg = 0; rg < 4; ++rg) {
        size_t row = m0 + (wr << 7) + (i << 4) + (g << 2) + rg;
        size_t col = n0 + (wc << 6) + (j << 4) + rr;
        int kb = (int)(row >> 8), t = (int)((row >> 4) & 15), r16 = (int)(row & 15);
        int h = (int)(col >> 6), ch = (int)(col & 63);
        size_t odx = ((((size_t)kb * 16 + h) * 16 + t) << 10)
                   + ((ch >> 5) << 9) + (((ch >> 3) & 3) << 7) + (r16 << 3) + (ch & 7);
        Cpk[odx] = f2bf(acc[i][j][rg]);
      }

  // ---------------- Q-projection coda: 64 blocks, one tile PER WAVE (r12) ----------------
  if ((wg & 63) < 8) {
    const int ti = ((wg >> 6) << 6) + ((wg & 7) << 3) + wid;   // 0..511, bijective
    const int mq = ti >> 6, nq = ti & 63;
    const ushort_t* qa = qA + (size_t)(mq * 16 + rr) * 1024 + g * 8;
    const ushort_t* qb = qB + (size_t)(nq * 16 + rr) * 1024 + g * 8;
    f32x4 qacc0 = (f32x4){0.f, 0.f, 0.f, 0.f};
    f32x4 qacc1 = (f32x4){0.f, 0.f, 0.f, 0.f};
    #pragma unroll
    for (int kk = 0; kk < 32; kk += 2) {
      bf16x8 a0 = *(const bf16x8*)(qa + kk * 32);
      bf16x8 b0 = *(const bf16x8*)(qb + kk * 32);
      bf16x8 a1 = *(const bf16x8*)(qa + kk * 32 + 32);
      bf16x8 b1 = *(const bf16x8*)(qb + kk * 32 + 32);
      qacc0 = __builtin_amdgcn_mfma_f32_16x16x32_bf16(a0, b0, qacc0, 0, 0, 0);
      qacc1 = __builtin_amdgcn_mfma_f32_16x16x32_bf16(a1, b1, qacc1, 0, 0, 0);
    }
    #pragma unroll
    for (int rg = 0; rg < 4; ++rg)
      qC[(size_t)(mq * 16 + (g << 2) + rg) * 1024 + nq * 16 + rr] = f2bf(qacc0[rg] + qacc1[rg]);
  }
}

// ---------------------------------------------------------------------------
// K4a: scores kernel (packed K loads, static indexing).
// ---------------------------------------------------------------------------
__global__ __launch_bounds__(256, 3) void scores_kernel(const ushort_t* __restrict__ qp,   // [128][1024]
                                                        const ushort_t* __restrict__ kpk,  // packed
                                                        ushort_t* __restrict__ wbuf) {     // [128][128][256]
  __shared__ float pbuf[2][16][258];

  const int tid = threadIdx.x, lane = tid & 63, wid = tid >> 6;
  const int g = lane >> 4, rr = lane & 15;

  const int b = blockIdx.x;
  const int wg = (b & 7) * 128 + (b >> 3);
  const int kb = wg >> 3;
  const int q0 = (wg & 7) << 4;

  const int hs = wid;

  float w_acc[16][4];
  #pragma unroll
  for (int t = 0; t < 16; ++t)
    #pragma unroll
    for (int r = 0; r < 4; ++r) w_acc[t][r] = 0.f;

  const ushort_t* qrow = qp + (size_t)(q0 + rr) * 1024;
  const ushort_t* kbb  = kpk + ((size_t)kb * 16) * 16384 + g * 128 + rr * 8;

  for (int hp = 0; hp < 4; ++hp) {
    const int h = hp * 4 + hs;
    const int co = h * 64 + g * 8;
    bf16x8 aq0 = *(const bf16x8*)(qrow + co);
    bf16x8 aq1 = *(const bf16x8*)(qrow + co + 32);
    const ushort_t* hb = kbb + (size_t)h * 16384;
    f32x4 s[16];
    #pragma unroll
    for (int t = 0; t < 16; ++t) {
      bf16x8 b0 = *(const bf16x8*)(hb + t * 1024);
      bf16x8 b1 = *(const bf16x8*)(hb + t * 1024 + 512);
      f32x4 a = (f32x4){0.f, 0.f, 0.f, 0.f};
      a = __builtin_amdgcn_mfma_f32_16x16x32_bf16(aq0, b0, a, 0, 0, 0);
      a = __builtin_amdgcn_mfma_f32_16x16x32_bf16(aq1, b1, a, 0, 0, 0);
      s[t] = a;
    }
    #pragma unroll
    for (int r = 0; r < 4; ++r) {
      float mx = s[0][r];
      #pragma unroll
      for (int t = 1; t < 16; ++t) mx = fmaxf(mx, s[t][r]);
      mx = fmaxf(mx, __shfl_xor(mx, 1));
      mx = fmaxf(mx, __shfl_xor(mx, 2));
      mx = fmaxf(mx, __shfl_xor(mx, 4));
      mx = fmaxf(mx, __shfl_xor(mx, 8));
      float sum = 0.f;
      float e[16];
      #pragma unroll
      for (int t = 0; t < 16; ++t) {
        e[t] = __expf((s[t][r] - mx) * 0.125f);
        sum += e[t];
      }
      sum += __shfl_xor(sum, 1);
      sum += __shfl_xor(sum, 2);
      sum += __shfl_xor(sum, 4);
      sum += __shfl_xor(sum, 8);
      float inv = 1.0f / sum;
      #pragma unroll
      for (int t = 0; t < 16; ++t) w_acc[t][r] += e[t] * inv;
    }
  }

  __syncthreads();
  if (hs >= 2) {
    #pragma unroll
    for (int t = 0; t < 16; ++t)
      #pragma unroll
      for (int r = 0; r < 4; ++r)
        pbuf[hs - 2][(g << 2) + r][t * 16 + rr] = w_acc[t][r];
  }
  __syncthreads();
  if (hs < 2) {
    #pragma unroll
    for (int t = 0; t < 16; ++t)
      #pragma unroll
      for (int r = 0; r < 4; ++r)
        w_acc[t][r] += pbuf[hs][(g << 2) + r][t * 16 + rr];
    if (hs == 1) {
      #pragma unroll
      for (int t = 0; t < 16; ++t)
        #pragma unroll
        for (int r = 0; r < 4; ++r)
          pbuf[1][(g << 2) + r][t * 16 + rr] = w_acc[t][r];
    }
  }
  __syncthreads();
  if (hs == 0) {
    ushort_t* wb = wbuf + (size_t)kb * 32768;
    #pragma unroll
    for (int t = 0; t < 16; ++t)
      #pragma unroll
      for (int r = 0; r < 4; ++r) {
        float v = w_acc[t][r] + pbuf[1][(g << 2) + r][t * 16 + rr];
        wb[(size_t)(q0 + (g << 2) + r) * 256 + t * 16 + rr] = f2bf(v);
      }
  }
}

// ---------------------------------------------------------------------------
// K4b: PV kernel (r12 version — measured-good).
// ---------------------------------------------------------------------------
__global__ __launch_bounds__(256, 4) void pv_kernel(const ushort_t* __restrict__ wbuf, // [128][128][256]
                                                    const float* __restrict__ kx,      // [32768][1024]
                                                    float* __restrict__ xout) {        // [128][128][1024]
  const int tid = threadIdx.x, lane = tid & 63, wid = tid >> 6;
  const int g = lane >> 4, rr = lane & 15;

  const int b = blockIdx.x;
  const int wg = (b & 7) * 128 + (b >> 3);
  const int kb = wg >> 3;
  const int c0 = (wg & 7) * 128;

  const int wr = wid >> 1, wc = wid & 1;

  f32x4 acc[4][4];
  #pragma unroll
  for (int i = 0; i < 4; ++i)
    #pragma unroll
    for (int j = 0; j < 4; ++j) acc[i][j] = (f32x4){0.f, 0.f, 0.f, 0.f};

  const ushort_t* wb = wbuf + (size_t)kb * 32768;
  const float* kxb = kx + (size_t)kb * 256 * 1024;

  for (int nc = 0; nc < 8; ++nc) {
    const int n0 = nc * 32 + g * 8;
    bf16x8 af[4];
    #pragma unroll
    for (int i = 0; i < 4; ++i) {
      int q = (wr << 6) + (i << 4) + rr;
      af[i] = *(const bf16x8*)(wb + (size_t)q * 256 + n0);
    }
    #pragma unroll
    for (int j = 0; j < 4; ++j) {
      int c = c0 + (wc << 6) + (j << 4) + rr;
      const float* src = kxb + (size_t)n0 * 1024 + c;
      float f[8];
      #pragma unroll
      for (int jj = 0; jj < 8; ++jj) f[jj] = src[(size_t)jj * 1024];
      bf16x8 bb;
      #pragma unroll
      for (int jj = 0; jj < 8; ++jj) bb[jj] = (__bf16)f[jj];
      #pragma unroll
      for (int i = 0; i < 4; ++i)
        acc[i][j] = __builtin_amdgcn_mfma_f32_16x16x32_bf16(af[i], bb, acc[i][j], 0, 0, 0);
    }
  }

  #pragma unroll
  for (int i = 0; i < 4; ++i)
    #pragma unroll
    for (int j = 0; j < 4; ++j)
      #pragma unroll
      for (int rg = 0; rg < 4; ++rg) {
        int q = (wr << 6) + (i << 4) + (g << 2) + rg;
        int c = c0 + (wc << 6) + (j << 4) + rr;
        xout[((size_t)q * 128 + kb) * 1024 + c] = acc[i][j][rg];
      }
}

// ---------------------------------------------------------------------------
// launcher
// ---------------------------------------------------------------------------
extern "C" void kernel_launch(void* const* d_in, const int* in_sizes, int n_in,
                              void* d_out, int out_size, void* d_ws, size_t ws_size,
                              hipStream_t stream) {
  const float* qx = (const float*)d_in[0];
  const float* kx = (const float*)d_in[1];
  const float* gq = (const float*)d_in[2];
  const float* bq = (const float*)d_in[3];
  const float* gk = (const float*)d_in[4];
  const float* bk = (const float*)d_in[5];
  const float* Wq = (const float*)d_in[6];
  const float* Wk = (const float*)d_in[7];

  char* ws = (char*)d_ws;
  // ws layout (total 72.25 MiB, r12 scheme):
  //   [0, 64M)            kkp   : PACKED K-projection bf16 (live: gemm256 -> scores)
  //   [64M, 64M+256K)     qproj : Q-projection bf16 [128][1024] (live: gemm256 -> scores)
  //   [64M+256K, +8M)     wbuf  : head-summed weights bf16 [128][128][256] (live: scores -> pv)
  //     aliased inside wbuf (dead before scores runs):
  //       qln @wbuf+0      [128][1024] bf16  (live: ln -> gemm256 coda)
  //       Wqb @wbuf+256K   [1024][1024] bf16 (live: cvt -> gemm256 coda)
  //       Wkb @wbuf+2.25M  [1024][1024] bf16 (live: cvt -> gemm256)
  ushort_t* kkp   = (ushort_t*)(ws);
  ushort_t* qproj = (ushort_t*)(ws + 67108864);
  ushort_t* wbuf  = (ushort_t*)(ws + 67371008);
  ushort_t* qln   = (ushort_t*)(ws + 67371008);
  ushort_t* Wqb   = (ushort_t*)(ws + 67371008 + 262144);
  ushort_t* Wkb   = (ushort_t*)(ws + 67371008 + 2359296);
  // kln (bf16, 64 MiB) lives in d_out; dead after gemm256, overwritten by pv.
  ushort_t* kln  = (ushort_t*)d_out;
  float*    xout = (float*)d_out;

  cvt_bf16_kernel<<<2048, 256, 0, stream>>>(Wq, Wk, Wqb, Wkb);
  ln_kernel<<<8192 + 32, 256, 0, stream>>>(kx, qx, gk, bk, gq, bq, kln, qln);
  gemm256_kernel<<<512, 512, 0, stream>>>(kln, Wkb, kkp, qln, Wqb, qproj, 32768, 1024);
  scores_kernel<<<1024, 256, 0, stream>>>(qproj, kkp, wbuf);
  pv_kernel<<<1024, 256, 0, stream>>>(wbuf, kx, xout);
}

// Round 23
// 251.476 us; speedup vs baseline: 1.0573x; 1.0363x over previous
//
#include <hip/hip_runtime.h>

// Problem constants: Bq=128, Bk=128, Nk=256, C=1024, H=16, hd=64, scale=0.125, eps=1e-5.

typedef unsigned short ushort_t;
typedef __bf16 bf16x8 __attribute__((ext_vector_type(8)));
typedef float f32x4 __attribute__((ext_vector_type(4)));

#define AS1 __attribute__((address_space(1)))
#define AS3 __attribute__((address_space(3)))

__device__ __forceinline__ void gload_lds16(const void* g, void* l) {
  __builtin_amdgcn_global_load_lds((const AS1 unsigned int*)g, (AS3 unsigned int*)l, 16, 0, 0);
}

__device__ __forceinline__ ushort_t f2bf(float f) {
  unsigned u = __float_as_uint(f);
  unsigned r = u + 0x7FFFu + ((u >> 16) & 1u);
  return (ushort_t)(r >> 16);
}

// ---------------------------------------------------------------------------
// K1: fused front kernel (ONE dispatch).
//  blocks 0..8191     : kx rows -> kln  (gk, bk)   one wave per row
//  blocks 8192..8223  : qx rows -> qln  (gq, bq)   one wave per row
//  blocks 8224..10271 : weight cvt fp32->bf16 (Wq then Wk, 1024 blocks each)
// ---------------------------------------------------------------------------
__global__ __launch_bounds__(256) void ln_kernel(const float* __restrict__ kx,
                                                 const float* __restrict__ qx,
                                                 const float* __restrict__ gk,
                                                 const float* __restrict__ bk,
                                                 const float* __restrict__ gq,
                                                 const float* __restrict__ bq,
                                                 const float* __restrict__ Wq,
                                                 const float* __restrict__ Wk,
                                                 ushort_t* __restrict__ Wqb,
                                                 ushort_t* __restrict__ Wkb,
                                                 ushort_t* __restrict__ kln,
                                                 ushort_t* __restrict__ qln) {
  const int tid = threadIdx.x, lane = tid & 63, wid = tid >> 6;

  if (blockIdx.x >= 8224) {
    // ---------------- weight cvt path ----------------
    const int cb = blockIdx.x - 8224;            // 0..2047
    const float* src; ushort_t* dst; int i;
    if (cb < 1024) { src = Wq; dst = Wqb; i = cb * 256 + tid; }
    else           { src = Wk; dst = Wkb; i = (cb - 1024) * 256 + tid; }
    float4 v = ((const float4*)src)[i];
    ushort4 o;
    o.x = f2bf(v.x); o.y = f2bf(v.y); o.z = f2bf(v.z); o.w = f2bf(v.w);
    ((ushort4*)dst)[i] = o;
    return;
  }

  const float* src; ushort_t* dst; const float* gp; const float* bp;
  if (blockIdx.x < 8192) {
    const int row = blockIdx.x * 4 + wid;
    src = kx + (size_t)row * 1024; dst = kln + (size_t)row * 1024; gp = gk; bp = bk;
  } else {
    const int row = (blockIdx.x - 8192) * 4 + wid;
    src = qx + (size_t)row * 1024; dst = qln + (size_t)row * 1024; gp = gq; bp = bq;
  }
  const int c0 = lane * 4;

  float4 v0 = *(const float4*)(src + c0);
  float4 v1 = *(const float4*)(src + c0 + 256);
  float4 v2 = *(const float4*)(src + c0 + 512);
  float4 v3 = *(const float4*)(src + c0 + 768);

  float s  = (v0.x + v0.y + v0.z + v0.w) + (v1.x + v1.y + v1.z + v1.w)
           + (v2.x + v2.y + v2.z + v2.w) + (v3.x + v3.y + v3.z + v3.w);
  float s2 = (v0.x*v0.x + v0.y*v0.y + v0.z*v0.z + v0.w*v0.w)
           + (v1.x*v1.x + v1.y*v1.y + v1.z*v1.z + v1.w*v1.w)
           + (v2.x*v2.x + v2.y*v2.y + v2.z*v2.z + v2.w*v2.w)
           + (v3.x*v3.x + v3.y*v3.y + v3.z*v3.z + v3.w*v3.w);
  #pragma unroll
  for (int off = 1; off < 64; off <<= 1) {
    s  += __shfl_xor(s, off);
    s2 += __shfl_xor(s2, off);
  }
  const float mean = s * (1.0f / 1024.0f);
  const float var  = s2 * (1.0f / 1024.0f) - mean * mean;
  const float rstd = rsqrtf(var + 1e-5f);

  float4 g0 = *(const float4*)(gp + c0);
  float4 g1 = *(const float4*)(gp + c0 + 256);
  float4 g2 = *(const float4*)(gp + c0 + 512);
  float4 g3 = *(const float4*)(gp + c0 + 768);
  float4 b0 = *(const float4*)(bp + c0);
  float4 b1 = *(const float4*)(bp + c0 + 256);
  float4 b2 = *(const float4*)(bp + c0 + 512);
  float4 b3 = *(const float4*)(bp + c0 + 768);

  ushort4 o0, o1, o2, o3;
  o0.x = f2bf((v0.x - mean) * rstd * g0.x + b0.x);
  o0.y = f2bf((v0.y - mean) * rstd * g0.y + b0.y);
  o0.z = f2bf((v0.z - mean) * rstd * g0.z + b0.z);
  o0.w = f2bf((v0.w - mean) * rstd * g0.w + b0.w);
  o1.x = f2bf((v1.x - mean) * rstd * g1.x + b1.x);
  o1.y = f2bf((v1.y - mean) * rstd * g1.y + b1.y);
  o1.z = f2bf((v1.z - mean) * rstd * g1.z + b1.z);
  o1.w = f2bf((v1.w - mean) * rstd * g1.w + b1.w);
  o2.x = f2bf((v2.x - mean) * rstd * g2.x + b2.x);
  o2.y = f2bf((v2.y - mean) * rstd * g2.y + b2.y);
  o2.z = f2bf((v2.z - mean) * rstd * g2.z + b2.z);
  o2.w = f2bf((v2.w - mean) * rstd * g2.w + b2.w);
  o3.x = f2bf((v3.x - mean) * rstd * g3.x + b3.x);
  o3.y = f2bf((v3.y - mean) * rstd * g3.y + b3.y);
  o3.z = f2bf((v3.z - mean) * rstd * g3.z + b3.z);
  o3.w = f2bf((v3.w - mean) * rstd * g3.w + b3.w);

  *(ushort4*)(dst + c0)       = o0;
  *(ushort4*)(dst + c0 + 256) = o1;
  *(ushort4*)(dst + c0 + 512) = o2;
  *(ushort4*)(dst + c0 + 768) = o3;
}

// ---------------------------------------------------------------------------
// K3: K-projection GEMM (r17/r20 coarse counted-vmcnt schedule, BK=64 —
// measured best across 6 schedule variants) + r12's spread Q-coda.
// REFUTED alternatives (measured): 4-phase barriers (r19, 95), BK=32 2-blk/CU
// (r21, 95.5), 2-buf vmcnt (r10, 119), B-from-regs (r13, 98).
// Launch bound (512,2): cap 256 VGPR — (512,4) spilled 30x (r9).
// ---------------------------------------------------------------------------
__global__ __launch_bounds__(512, 2) void gemm256_kernel(const ushort_t* __restrict__ A,
                                                         const ushort_t* __restrict__ Bt,
                                                         ushort_t* __restrict__ Cpk,
                                                         const ushort_t* __restrict__ qA,
                                                         const ushort_t* __restrict__ qB,
                                                         ushort_t* __restrict__ qC,
                                                         int M, int N) {
  __shared__ ushort_t Abuf[3][16384];   // 3 x 256x64 bf16 = 96KB
  __shared__ ushort_t Bbuf[2][16384];   // 2 x 256x64 bf16 = 64KB

  const int tid = threadIdx.x, lane = tid & 63, wid = tid >> 6;
  const int g = lane >> 4, rr = lane & 15;
  const int wr = wid >> 2, wc = wid & 3;

  const int Mt = M >> 8, Nt = N >> 8;
  const int nwg = Mt * Nt;
  const int qq = nwg >> 3, r8 = nwg & 7;
  const int xcd = blockIdx.x & 7, idx = blockIdx.x >> 3;
  const int wg = (xcd < r8 ? xcd * (qq + 1) : r8 * (qq + 1) + (xcd - r8) * qq) + idx;
  const int mt = wg / Nt, nt = wg - mt * Nt;
  const size_t m0 = (size_t)mt << 8, n0 = (size_t)nt << 8;

  const ushort_t* Abase = A  + m0 * 1024;
  const ushort_t* Bbase = Bt + n0 * 1024;

  f32x4 acc[8][4];
  #pragma unroll
  for (int i = 0; i < 8; ++i)
    #pragma unroll
    for (int j = 0; j < 4; ++j) acc[i][j] = (f32x4){0.f, 0.f, 0.f, 0.f};

  auto stA = [&](int kt) {
    ushort_t* dst = &Abuf[kt % 3][0];
    #pragma unroll
    for (int l = 0; l < 4; ++l) {
      int ix = l * 512 + tid;
      int r  = ix >> 3;
      int gs = (ix & 7) ^ (((r >> 2) & 1) << 1);
      gload_lds16(Abase + (size_t)r * 1024 + (kt << 6) + (gs << 3), dst + ix * 8);
    }
  };
  auto stB = [&](int kt) {
    ushort_t* dst = &Bbuf[kt & 1][0];
    #pragma unroll
    for (int l = 0; l < 4; ++l) {
      int ix = l * 512 + tid;
      int r  = ix >> 3;
      int gs = (ix & 7) ^ (((r >> 2) & 1) << 1);
      gload_lds16(Bbase + (size_t)r * 1024 + (kt << 6) + (gs << 3), dst + ix * 8);
    }
  };

  stA(0); stB(0); stA(1);
  asm volatile("s_waitcnt vmcnt(4)" ::: "memory");
  __builtin_amdgcn_s_barrier();

  const int sw = ((rr >> 2) & 1) << 1;

  #pragma unroll 1
  for (int j = 0; j < 16; ++j) {
    const ushort_t* as = &Abuf[j % 3][0];
    const ushort_t* bs = &Bbuf[j & 1][0];

    {
      bf16x8 af[8], bf[4];
      #pragma unroll
      for (int i = 0; i < 8; ++i) {
        int r = (wr << 7) + (i << 4) + rr;
        af[i] = *(const bf16x8*)&as[(r << 6) + ((g ^ sw) << 3)];
      }
      #pragma unroll
      for (int jj = 0; jj < 4; ++jj) {
        int r = (wc << 6) + (jj << 4) + rr;
        bf[jj] = *(const bf16x8*)&bs[(r << 6) + ((g ^ sw) << 3)];
      }
      if (j < 15) stB(j + 1);
      if (j < 14) stA(j + 2);
      __builtin_amdgcn_s_setprio(1);
      #pragma unroll
      for (int i = 0; i < 8; ++i)
        #pragma unroll
        for (int jj = 0; jj < 4; ++jj)
          acc[i][jj] = __builtin_amdgcn_mfma_f32_16x16x32_bf16(af[i], bf[jj], acc[i][jj], 0, 0, 0);
      __builtin_amdgcn_s_setprio(0);
    }
    {
      bf16x8 af[8], bf[4];
      #pragma unroll
      for (int i = 0; i < 8; ++i) {
        int r = (wr << 7) + (i << 4) + rr;
        af[i] = *(const bf16x8*)&as[(r << 6) + (((4 + g) ^ sw) << 3)];
      }
      #pragma unroll
      for (int jj = 0; jj < 4; ++jj) {
        int r = (wc << 6) + (jj << 4) + rr;
        bf[jj] = *(const bf16x8*)&bs[(r << 6) + (((4 + g) ^ sw) << 3)];
      }
      __builtin_amdgcn_s_setprio(1);
      #pragma unroll
      for (int i = 0; i < 8; ++i)
        #pragma unroll
        for (int jj = 0; jj < 4; ++jj)
          acc[i][jj] = __builtin_amdgcn_mfma_f32_16x16x32_bf16(af[i], bf[jj], acc[i][jj], 0, 0, 0);
      __builtin_amdgcn_s_setprio(0);
      if (j < 14) {
        asm volatile("s_waitcnt vmcnt(4)" ::: "memory");
        __builtin_amdgcn_s_barrier();
      } else if (j == 14) {
        asm volatile("s_waitcnt vmcnt(0)" ::: "memory");
        __builtin_amdgcn_s_barrier();
      }
    }
  }

  // packed epilogue: idx = ((kb*16+h)*16+t)*1024 + half*512 + g*128 + r16*8 + e
  #pragma unroll
  for (int i = 0; i < 8; ++i)
    #pragma unroll
    for (int j = 0; j < 4; ++j)
      #pragma unroll
      for (int rg = 0; rg < 4; ++rg) {
        size_t row = m0 + (wr << 7) + (i << 4) + (g << 2) + rg;
        size_t col = n0 + (wc << 6) + (j << 4) + rr;
        int kb = (int)(row >> 8), t = (int)((row >> 4) & 15), r16 = (int)(row & 15);
        int h = (int)(col >> 6), ch = (int)(col & 63);
        size_t odx = ((((size_t)kb * 16 + h) * 16 + t) << 10)
                   + ((ch >> 5) << 9) + (((ch >> 3) & 3) << 7) + (r16 << 3) + (ch & 7);
        Cpk[odx] = f2bf(acc[i][j][rg]);
      }

  // ---------------- Q-projection coda: 64 blocks, one tile PER WAVE (r12) ----------------
  if ((wg & 63) < 8) {
    const int ti = ((wg >> 6) << 6) + ((wg & 7) << 3) + wid;   // 0..511, bijective
    const int mq = ti >> 6, nq = ti & 63;
    const ushort_t* qa = qA + (size_t)(mq * 16 + rr) * 1024 + g * 8;
    const ushort_t* qb = qB + (size_t)(nq * 16 + rr) * 1024 + g * 8;
    f32x4 qacc0 = (f32x4){0.f, 0.f, 0.f, 0.f};
    f32x4 qacc1 = (f32x4){0.f, 0.f, 0.f, 0.f};
    #pragma unroll
    for (int kk = 0; kk < 32; kk += 2) {
      bf16x8 a0 = *(const bf16x8*)(qa + kk * 32);
      bf16x8 b0 = *(const bf16x8*)(qb + kk * 32);
      bf16x8 a1 = *(const bf16x8*)(qa + kk * 32 + 32);
      bf16x8 b1 = *(const bf16x8*)(qb + kk * 32 + 32);
      qacc0 = __builtin_amdgcn_mfma_f32_16x16x32_bf16(a0, b0, qacc0, 0, 0, 0);
      qacc1 = __builtin_amdgcn_mfma_f32_16x16x32_bf16(a1, b1, qacc1, 0, 0, 0);
    }
    #pragma unroll
    for (int rg = 0; rg < 4; ++rg)
      qC[(size_t)(mq * 16 + (g << 2) + rg) * 1024 + nq * 16 + rr] = f2bf(qacc0[rg] + qacc1[rg]);
  }
}

// ---------------------------------------------------------------------------
// K4a: scores kernel (packed K loads, static indexing).
// ---------------------------------------------------------------------------
__global__ __launch_bounds__(256, 3) void scores_kernel(const ushort_t* __restrict__ qp,   // [128][1024]
                                                        const ushort_t* __restrict__ kpk,  // packed
                                                        ushort_t* __restrict__ wbuf) {     // [128][128][256]
  __shared__ float pbuf[2][16][258];

  const int tid = threadIdx.x, lane = tid & 63, wid = tid >> 6;
  const int g = lane >> 4, rr = lane & 15;

  const int b = blockIdx.x;
  const int wg = (b & 7) * 128 + (b >> 3);
  const int kb = wg >> 3;
  const int q0 = (wg & 7) << 4;

  const int hs = wid;

  float w_acc[16][4];
  #pragma unroll
  for (int t = 0; t < 16; ++t)
    #pragma unroll
    for (int r = 0; r < 4; ++r) w_acc[t][r] = 0.f;

  const ushort_t* qrow = qp + (size_t)(q0 + rr) * 1024;
  const ushort_t* kbb  = kpk + ((size_t)kb * 16) * 16384 + g * 128 + rr * 8;

  for (int hp = 0; hp < 4; ++hp) {
    const int h = hp * 4 + hs;
    const int co = h * 64 + g * 8;
    bf16x8 aq0 = *(const bf16x8*)(qrow + co);
    bf16x8 aq1 = *(const bf16x8*)(qrow + co + 32);
    const ushort_t* hb = kbb + (size_t)h * 16384;
    f32x4 s[16];
    #pragma unroll
    for (int t = 0; t < 16; ++t) {
      bf16x8 b0 = *(const bf16x8*)(hb + t * 1024);
      bf16x8 b1 = *(const bf16x8*)(hb + t * 1024 + 512);
      f32x4 a = (f32x4){0.f, 0.f, 0.f, 0.f};
      a = __builtin_amdgcn_mfma_f32_16x16x32_bf16(aq0, b0, a, 0, 0, 0);
      a = __builtin_amdgcn_mfma_f32_16x16x32_bf16(aq1, b1, a, 0, 0, 0);
      s[t] = a;
    }
    #pragma unroll
    for (int r = 0; r < 4; ++r) {
      float mx = s[0][r];
      #pragma unroll
      for (int t = 1; t < 16; ++t) mx = fmaxf(mx, s[t][r]);
      mx = fmaxf(mx, __shfl_xor(mx, 1));
      mx = fmaxf(mx, __shfl_xor(mx, 2));
      mx = fmaxf(mx, __shfl_xor(mx, 4));
      mx = fmaxf(mx, __shfl_xor(mx, 8));
      float sum = 0.f;
      float e[16];
      #pragma unroll
      for (int t = 0; t < 16; ++t) {
        e[t] = __expf((s[t][r] - mx) * 0.125f);
        sum += e[t];
      }
      sum += __shfl_xor(sum, 1);
      sum += __shfl_xor(sum, 2);
      sum += __shfl_xor(sum, 4);
      sum += __shfl_xor(sum, 8);
      float inv = 1.0f / sum;
      #pragma unroll
      for (int t = 0; t < 16; ++t) w_acc[t][r] += e[t] * inv;
    }
  }

  __syncthreads();
  if (hs >= 2) {
    #pragma unroll
    for (int t = 0; t < 16; ++t)
      #pragma unroll
      for (int r = 0; r < 4; ++r)
        pbuf[hs - 2][(g << 2) + r][t * 16 + rr] = w_acc[t][r];
  }
  __syncthreads();
  if (hs < 2) {
    #pragma unroll
    for (int t = 0; t < 16; ++t)
      #pragma unroll
      for (int r = 0; r < 4; ++r)
        w_acc[t][r] += pbuf[hs][(g << 2) + r][t * 16 + rr];
    if (hs == 1) {
      #pragma unroll
      for (int t = 0; t < 16; ++t)
        #pragma unroll
        for (int r = 0; r < 4; ++r)
          pbuf[1][(g << 2) + r][t * 16 + rr] = w_acc[t][r];
    }
  }
  __syncthreads();
  if (hs == 0) {
    ushort_t* wb = wbuf + (size_t)kb * 32768;
    #pragma unroll
    for (int t = 0; t < 16; ++t)
      #pragma unroll
      for (int r = 0; r < 4; ++r) {
        float v = w_acc[t][r] + pbuf[1][(g << 2) + r][t * 16 + rr];
        wb[(size_t)(q0 + (g << 2) + r) * 256 + t * 16 + rr] = f2bf(v);
      }
  }
}

// ---------------------------------------------------------------------------
// K4b: PV kernel (r12 version — measured-good).
// ---------------------------------------------------------------------------
__global__ __launch_bounds__(256, 4) void pv_kernel(const ushort_t* __restrict__ wbuf, // [128][128][256]
                                                    const float* __restrict__ kx,      // [32768][1024]
                                                    float* __restrict__ xout) {        // [128][128][1024]
  const int tid = threadIdx.x, lane = tid & 63, wid = tid >> 6;
  const int g = lane >> 4, rr = lane & 15;

  const int b = blockIdx.x;
  const int wg = (b & 7) * 128 + (b >> 3);
  const int kb = wg >> 3;
  const int c0 = (wg & 7) * 128;

  const int wr = wid >> 1, wc = wid & 1;

  f32x4 acc[4][4];
  #pragma unroll
  for (int i = 0; i < 4; ++i)
    #pragma unroll
    for (int j = 0; j < 4; ++j) acc[i][j] = (f32x4){0.f, 0.f, 0.f, 0.f};

  const ushort_t* wb = wbuf + (size_t)kb * 32768;
  const float* kxb = kx + (size_t)kb * 256 * 1024;

  for (int nc = 0; nc < 8; ++nc) {
    const int n0 = nc * 32 + g * 8;
    bf16x8 af[4];
    #pragma unroll
    for (int i = 0; i < 4; ++i) {
      int q = (wr << 6) + (i << 4) + rr;
      af[i] = *(const bf16x8*)(wb + (size_t)q * 256 + n0);
    }
    #pragma unroll
    for (int j = 0; j < 4; ++j) {
      int c = c0 + (wc << 6) + (j << 4) + rr;
      const float* src = kxb + (size_t)n0 * 1024 + c;
      float f[8];
      #pragma unroll
      for (int jj = 0; jj < 8; ++jj) f[jj] = src[(size_t)jj * 1024];
      bf16x8 bb;
      #pragma unroll
      for (int jj = 0; jj < 8; ++jj) bb[jj] = (__bf16)f[jj];
      #pragma unroll
      for (int i = 0; i < 4; ++i)
        acc[i][j] = __builtin_amdgcn_mfma_f32_16x16x32_bf16(af[i], bb, acc[i][j], 0, 0, 0);
    }
  }

  #pragma unroll
  for (int i = 0; i < 4; ++i)
    #pragma unroll
    for (int j = 0; j < 4; ++j)
      #pragma unroll
      for (int rg = 0; rg < 4; ++rg) {
        int q = (wr << 6) + (i << 4) + (g << 2) + rg;
        int c = c0 + (wc << 6) + (j << 4) + rr;
        xout[((size_t)q * 128 + kb) * 1024 + c] = acc[i][j][rg];
      }
}

// ---------------------------------------------------------------------------
// launcher (4 dispatches)
// ---------------------------------------------------------------------------
extern "C" void kernel_launch(void* const* d_in, const int* in_sizes, int n_in,
                              void* d_out, int out_size, void* d_ws, size_t ws_size,
                              hipStream_t stream) {
  const float* qx = (const float*)d_in[0];
  const float* kx = (const float*)d_in[1];
  const float* gq = (const float*)d_in[2];
  const float* bq = (const float*)d_in[3];
  const float* gk = (const float*)d_in[4];
  const float* bk = (const float*)d_in[5];
  const float* Wq = (const float*)d_in[6];
  const float* Wk = (const float*)d_in[7];

  char* ws = (char*)d_ws;
  // ws layout (total 72.25 MiB, r12 scheme):
  //   [0, 64M)            kkp   : PACKED K-projection bf16 (live: gemm256 -> scores)
  //   [64M, 64M+256K)     qproj : Q-projection bf16 [128][1024] (live: gemm256 -> scores)
  //   [64M+256K, +8M)     wbuf  : head-summed weights bf16 [128][128][256] (live: scores -> pv)
  //     aliased inside wbuf (dead before scores runs):
  //       qln @wbuf+0      [128][1024] bf16  (live: ln -> gemm256 coda)
  //       Wqb @wbuf+256K   [1024][1024] bf16 (live: ln cvt-path -> gemm256 coda)
  //       Wkb @wbuf+2.25M  [1024][1024] bf16 (live: ln cvt-path -> gemm256)
  ushort_t* kkp   = (ushort_t*)(ws);
  ushort_t* qproj = (ushort_t*)(ws + 67108864);
  ushort_t* wbuf  = (ushort_t*)(ws + 67371008);
  ushort_t* qln   = (ushort_t*)(ws + 67371008);
  ushort_t* Wqb   = (ushort_t*)(ws + 67371008 + 262144);
  ushort_t* Wkb   = (ushort_t*)(ws + 67371008 + 2359296);
  // kln (bf16, 64 MiB) lives in d_out; dead after gemm256, overwritten by pv.
  ushort_t* kln  = (ushort_t*)d_out;
  float*    xout = (float*)d_out;

  ln_kernel<<<8192 + 32 + 2048, 256, 0, stream>>>(kx, qx, gk, bk, gq, bq, Wq, Wk,
                                                  Wqb, Wkb, kln, qln);
  gemm256_kernel<<<512, 512, 0, stream>>>(kln, Wkb, kkp, qln, Wqb, qproj, 32768, 1024);
  scores_kernel<<<1024, 256, 0, stream>>>(qproj, kkp, wbuf);
  pv_kernel<<<1024, 256, 0, stream>>>(wbuf, kx, xout);
}